// Round 15
// baseline (79.229 us; speedup 1.0000x reference)
//
#include <hip/hip_runtime.h>
#include <hip/hip_bf16.h>

typedef short bf16x8 __attribute__((ext_vector_type(8)));
typedef float f32x4 __attribute__((ext_vector_type(4)));

typedef __attribute__((address_space(3))) void as3_void;
typedef const __attribute__((address_space(1))) void as1_void;

static constexpr int D = 256;
static constexpr float INV_T = 10.0f;  // 1 / 0.1

__device__ __forceinline__ ushort f2bf(float f) {
  union { float f; unsigned u; } v; v.f = f;
  unsigned r = v.u + 0x7fffu + ((v.u >> 16) & 1u);  // RNE
  return (ushort)(r >> 16);
}

// Kernel 1: L2-normalize rows of images & captions -> bf16; diag logits (fp32).
__global__ __launch_bounds__(256) void normalize_kernel(
    const float* __restrict__ im, const float* __restrict__ cap,
    ushort* __restrict__ imn, ushort* __restrict__ capn,
    float* __restrict__ diag, int N) {
  int tid = blockIdx.x * 256 + threadIdx.x;
  int w = tid >> 6;
  int lane = threadIdx.x & 63;
  if (w >= N) return;
  float4 vi = ((const float4*)(im + (size_t)w * D))[lane];
  float4 vc = ((const float4*)(cap + (size_t)w * D))[lane];
  float ssi = vi.x*vi.x + vi.y*vi.y + vi.z*vi.z + vi.w*vi.w;
  float ssc = vc.x*vc.x + vc.y*vc.y + vc.z*vc.z + vc.w*vc.w;
  #pragma unroll
  for (int m = 1; m < 64; m <<= 1) {
    ssi += __shfl_xor(ssi, m);
    ssc += __shfl_xor(ssc, m);
  }
  float ri = 1.0f / fmaxf(sqrtf(ssi), 1e-12f);
  float rc = 1.0f / fmaxf(sqrtf(ssc), 1e-12f);
  float ax = vi.x*ri, ay = vi.y*ri, az = vi.z*ri, aw = vi.w*ri;
  float cx = vc.x*rc, cy = vc.y*rc, cz = vc.z*rc, cw = vc.w*rc;
  ushort4 ua, uc;
  ua.x = f2bf(ax); ua.y = f2bf(ay); ua.z = f2bf(az); ua.w = f2bf(aw);
  uc.x = f2bf(cx); uc.y = f2bf(cy); uc.z = f2bf(cz); uc.w = f2bf(cw);
  ((ushort4*)(imn + (size_t)w * D))[lane] = ua;
  ((ushort4*)(capn + (size_t)w * D))[lane] = uc;
  float d = ax*cx + ay*cy + az*cz + aw*cw;
  #pragma unroll
  for (int m = 1; m < 64; m <<= 1) d += __shfl_xor(d, m);
  if (lane == 0) diag[w] = d * INV_T;
}

// Kernel 2: persistent GEMM, r14 overlapped body, but 1024 threads = 16 waves
// = 4 waves/SIMD. The 1024-thread workgroup FORCES VGPR<=128 (16 waves must
// co-reside) -- TLP now covers pipe latency (m114): while 2 waves/SIMD run
// MFMA, the other 2 issue/wait LDS reads. Per-wave output 64x64 (acc 4x4 =
// 64 VGPR; total ~112). Shell r13/r14-proven: grid 256 (1/CU), bm x 4
// bn-tiles, A resident 8x[256][32] (128KB), B dbuf 2x[256][32] (32KB);
// swizzle verified 0 conflicts; single barrier per body; counted-vmcnt
// prologue; LGKM0 before the barrier makes cross-wave stage overwrite safe.
__global__ __launch_bounds__(1024) void gemm_exp_kernel(
    const ushort* __restrict__ A, const ushort* __restrict__ Bm,
    float* __restrict__ rowpart, float* __restrict__ colpart, int N) {
  __shared__ ushort As[8][256 * 32];  // 128 KB: A rows [bm*256,+256), all K
  __shared__ ushort Bs[2][256 * 32];  // 32 KB: B double buffer (BK=32)
  int bm = blockIdx.x >> 3;
  int grp = blockIdx.x & 7;   // B-sharing blocks land on one XCD (T1)
  int tid = threadIdx.x;
  int lane = tid & 63;
  int wv = tid >> 6;           // 0..15
  int wm = wv >> 2;            // 0..3 : rows [wm*64, +64)
  int wn = wv & 3;             // 0..3 : cols [wn*64, +64)

  // staging: thread covers row = tid>>2, unit = tid&3; LDS dest linear
  // (tid*16B); global source unit pre-swizzled (tid&3)^((tid>>3)&3)
  // (r6/r8-verified involution: slot(row,u) holds global u^((row>>1)&3)).
  int srow = tid >> 2;
  int scol = 8 * ((tid & 3) ^ ((tid >> 3) & 3));
  const ushort* agS = A + ((size_t)bm * 256 + srow) * D + scol;

  f32x4 acc[4][4];

  int rb = lane & 15;
  int kb = (lane >> 4) * 8;
  int cc = kb ^ (((rb >> 1) & 3) * 8);  // swizzled read column (elems)

#define VMWAIT(n) asm volatile("s_waitcnt vmcnt(" #n ")" ::: "memory")
#define LGKM0() asm volatile("s_waitcnt lgkmcnt(0)" ::: "memory")
#define BARRIER() asm volatile("s_barrier" ::: "memory")

#define STAGE_A(c)                                                           \
  __builtin_amdgcn_global_load_lds((as1_void*)(agS + (c) * 32),              \
      (as3_void*)(&As[c][tid * 8]), 16, 0, 0);

#define STAGE_B(buf, ptr, ch)                                                \
  __builtin_amdgcn_global_load_lds((as1_void*)((ptr) + (ch) * 32),           \
      (as3_void*)(&Bs[buf][tid * 8]), 16, 0, 0);

#define READ_B(BF, buf)                                                      \
  { _Pragma("unroll") for (int ni = 0; ni < 4; ++ni)                         \
      BF[ni] = *(const bf16x8*)(&Bs[buf][(wn * 64 + ni * 16 + rb) * 32 + cc]); }

#define READ_A(AF, kt)                                                       \
  { _Pragma("unroll") for (int mi = 0; mi < 4; ++mi)                         \
      AF[mi] = *(const bf16x8*)(&As[kt][(wm * 64 + mi * 16 + rb) * 32 + cc]); }

#define CLUSTER(mi, AF, FBC, CZ)                                             \
  __builtin_amdgcn_s_setprio(1);                                             \
  acc[mi][0] = __builtin_amdgcn_mfma_f32_16x16x32_bf16(AF[mi], FBC[0],       \
      (CZ) ? (f32x4){0.f,0.f,0.f,0.f} : acc[mi][0], 0, 0, 0);                \
  acc[mi][1] = __builtin_amdgcn_mfma_f32_16x16x32_bf16(AF[mi], FBC[1],       \
      (CZ) ? (f32x4){0.f,0.f,0.f,0.f} : acc[mi][1], 0, 0, 0);                \
  acc[mi][2] = __builtin_amdgcn_mfma_f32_16x16x32_bf16(AF[mi], FBC[2],       \
      (CZ) ? (f32x4){0.f,0.f,0.f,0.f} : acc[mi][2], 0, 0, 0);                \
  acc[mi][3] = __builtin_amdgcn_mfma_f32_16x16x32_bf16(AF[mi], FBC[3],       \
      (CZ) ? (f32x4){0.f,0.f,0.f,0.f} : acc[mi][3], 0, 0, 0);                \
  __builtin_amdgcn_s_setprio(0);

  // Body KT: stage chunk SCH -> buf SCH&1 (== KT&1, whose frags went to regs
  // last body); read af(KT) [immutable As] + FBN (stable buf, staged a body
  // ago); 16 MFMA; LGKM0 (FBN drained -> next body's overwrite safe);
  // vmcnt(0) (loads a body old); one barrier.
#define BODY(KT, FBC, FBN, SPTR, SCH, CZ)                                    \
  {                                                                          \
    STAGE_B(((SCH) & 1), SPTR, SCH)                                          \
    bf16x8 af[4];                                                            \
    READ_A(af, KT)                                                           \
    READ_B(FBN, ((KT) + 1) & 1)                                              \
    CLUSTER(0, af, FBC, CZ) CLUSTER(1, af, FBC, CZ)                          \
    CLUSTER(2, af, FBC, CZ) CLUSTER(3, af, FBC, CZ)                          \
    LGKM0(); __builtin_amdgcn_sched_barrier(0);                              \
    VMWAIT(0); BARRIER();                                                    \
  }

#define BT(j) (Bm + ((size_t)((grp * 4 + (j)) * 256) + srow) * D + scol)

#define EPILOGUE(BN) {                                                        \
    _Pragma("unroll")                                                         \
    for (int mi = 0; mi < 4; ++mi)                                            \
      _Pragma("unroll")                                                       \
      for (int ni = 0; ni < 4; ++ni)                                          \
        _Pragma("unroll")                                                     \
        for (int r = 0; r < 4; ++r)                                           \
          acc[mi][ni][r] = __expf(acc[mi][ni][r] * INV_T);                    \
    bool sb0 = (lane & 1) != 0, sb1 = (lane & 2) != 0;                        \
    _Pragma("unroll")                                                         \
    for (int mi = 0; mi < 4; ++mi) {                                          \
      float v0 = acc[mi][0][0] + acc[mi][1][0] + acc[mi][2][0] + acc[mi][3][0]; \
      float v1 = acc[mi][0][1] + acc[mi][1][1] + acc[mi][2][1] + acc[mi][3][1]; \
      float v2 = acc[mi][0][2] + acc[mi][1][2] + acc[mi][2][2] + acc[mi][3][2]; \
      float v3 = acc[mi][0][3] + acc[mi][1][3] + acc[mi][2][3] + acc[mi][3][3]; \
      float h0 = (sb0 ? v1 : v0) + __shfl_xor(sb0 ? v0 : v1, 1);              \
      float h1 = (sb0 ? v3 : v2) + __shfl_xor(sb0 ? v2 : v3, 1);              \
      float g  = (sb1 ? h1 : h0) + __shfl_xor(sb1 ? h0 : h1, 2);              \
      g += __shfl_xor(g, 4);                                                  \
      g += __shfl_xor(g, 8);                                                  \
      if ((lane & 12) == 0)                                                   \
        rowpart[(size_t)((BN) * 4 + wn) * N + bm * 256 + wm * 64 + mi * 16 +  \
                (lane >> 4) * 4 + (lane & 3)] = g;                            \
    }                                                                         \
    _Pragma("unroll")                                                         \
    for (int ni = 0; ni < 4; ++ni) {                                          \
      float v = 0.f;                                                          \
      _Pragma("unroll")                                                       \
      for (int mi = 0; mi < 4; ++mi)                                          \
        _Pragma("unroll")                                                     \
        for (int r = 0; r < 4; ++r)                                           \
          v += acc[mi][ni][r];                                                \
      v += __shfl_xor(v, 16); v += __shfl_xor(v, 32);                         \
      if (lane < 16)                                                          \
        colpart[(size_t)(bm * 4 + wm) * N + (BN) * 256 + wn * 64 + ni * 16 +  \
                lane] = v;                                                    \
    }                                                                         \
  }

  // Prologue: A all 8 slices (8 loads/thread) + B(tile0, chunks 0,1).
  STAGE_A(0) STAGE_A(1) STAGE_A(2) STAGE_A(3)
  STAGE_A(4) STAGE_A(5) STAGE_A(6) STAGE_A(7)
  STAGE_B(0, BT(0), 0)
  STAGE_B(1, BT(0), 1)
  VMWAIT(1); BARRIER();   // A + B chunk0 resident; chunk1 (newest 1) in flight

  bf16x8 fbA[4], fbB[4];
  READ_B(fbA, 0)   // chunk-0 frags for body 0

  for (int j = 0; j < 4; ++j) {
    const ushort* btc = BT(j);
    const ushort* btn = BT(j < 3 ? j + 1 : 3);  // j=3: wrap restage, never used
    BODY(0, fbA, fbB, btc, 2, 1)
    BODY(1, fbB, fbA, btc, 3, 0)
    BODY(2, fbA, fbB, btc, 4, 0)
    BODY(3, fbB, fbA, btc, 5, 0)
    BODY(4, fbA, fbB, btc, 6, 0)
    BODY(5, fbB, fbA, btc, 7, 0)
    BODY(6, fbA, fbB, btn, 0, 0)   // next-tile chunk0 -> buf0
    BODY(7, fbB, fbA, btn, 1, 0)   // next-tile chunk1 -> buf1
    EPILOGUE(grp * 4 + j)
  }
  VMWAIT(0);  // retire wrap stages + final stores

#undef EPILOGUE
#undef BT
#undef BODY
#undef CLUSTER
#undef READ_A
#undef READ_B
#undef STAGE_B
#undef STAGE_A
#undef VMWAIT
#undef LGKM0
#undef BARRIER
}

// Kernel 3: partial reduction + per-sample loss + atomic accumulate into out.
__global__ __launch_bounds__(256) void reduce_kernel(
    const float* __restrict__ rowpart, const float* __restrict__ colpart,
    const float* __restrict__ diag, float* __restrict__ out,
    int N, int NPr, int NPc) {
  __shared__ float redr[4][64], redc[4][64];
  int w = threadIdx.x >> 6, s = threadIdx.x & 63;
  int i = blockIdx.x * 64 + s;
  float rs = 0.f, cs = 0.f;
  for (int k = w; k < NPr; k += 4) rs += rowpart[(size_t)k * N + i];
  for (int k = w; k < NPc; k += 4) cs += colpart[(size_t)k * N + i];
  redr[w][s] = rs; redc[w][s] = cs;
  __syncthreads();
  if (w == 0) {
    float R = redr[0][s] + redr[1][s] + redr[2][s] + redr[3][s];
    float C = redc[0][s] + redc[1][s] + redc[2][s] + redc[3][s];
    float l = logf(R) + logf(C) - 2.0f * diag[i];
    #pragma unroll
    for (int m = 1; m < 64; m <<= 1) l += __shfl_xor(l, m);
    if (s == 0) atomicAdd(out, l * (0.5f / (float)N));
  }
}

extern "C" void kernel_launch(void* const* d_in, const int* in_sizes, int n_in,
                              void* d_out, int out_size, void* d_ws, size_t ws_size,
                              hipStream_t stream) {
  const float* images = (const float*)d_in[0];
  const float* captions = (const float*)d_in[1];
  int N = in_sizes[0] / D;   // 8192
  int NPr = 128;             // 32 bn-tiles x 4 wn
  int NPc = 128;             // 32 bm-blocks x 4 wm
  char* w = (char*)d_ws;
  size_t off = 0;
  ushort* imn  = (ushort*)(w + off); off += (size_t)N * D * 2;
  ushort* capn = (ushort*)(w + off); off += (size_t)N * D * 2;
  float* diag    = (float*)(w + off); off += (size_t)N * 4;
  float* rowpart = (float*)(w + off); off += (size_t)NPr * N * 4;
  float* colpart = (float*)(w + off); off += (size_t)NPc * N * 4;
  float* out = (float*)d_out;

  normalize_kernel<<<N / 4, 256, 0, stream>>>(images, captions, imn, capn, diag, N);
  gemm_exp_kernel<<<256, 1024, 0, stream>>>(imn, capn, rowpart, colpart, N);
  hipMemsetAsync(out, 0, sizeof(float), stream);
  reduce_kernel<<<N / 64, 256, 0, stream>>>(rowpart, colpart, diag, out, N, NPr, NPc);
}

// Round 16
// 68.283 us; speedup vs baseline: 1.1603x; 1.1603x over previous
//
#include <hip/hip_runtime.h>
#include <hip/hip_bf16.h>

typedef short bf16x8 __attribute__((ext_vector_type(8)));
typedef float f32x4 __attribute__((ext_vector_type(4)));

typedef __attribute__((address_space(3))) void as3_void;
typedef const __attribute__((address_space(1))) void as1_void;

static constexpr int D = 256;
static constexpr float INV_T = 10.0f;  // 1 / 0.1

__device__ __forceinline__ ushort f2bf(float f) {
  union { float f; unsigned u; } v; v.f = f;
  unsigned r = v.u + 0x7fffu + ((v.u >> 16) & 1u);  // RNE
  return (ushort)(r >> 16);
}

// Kernel 1: L2-normalize rows of images & captions -> bf16; diag logits (fp32).
__global__ __launch_bounds__(256) void normalize_kernel(
    const float* __restrict__ im, const float* __restrict__ cap,
    ushort* __restrict__ imn, ushort* __restrict__ capn,
    float* __restrict__ diag, int N) {
  int tid = blockIdx.x * 256 + threadIdx.x;
  int w = tid >> 6;
  int lane = threadIdx.x & 63;
  if (w >= N) return;
  float4 vi = ((const float4*)(im + (size_t)w * D))[lane];
  float4 vc = ((const float4*)(cap + (size_t)w * D))[lane];
  float ssi = vi.x*vi.x + vi.y*vi.y + vi.z*vi.z + vi.w*vi.w;
  float ssc = vc.x*vc.x + vc.y*vc.y + vc.z*vc.z + vc.w*vc.w;
  #pragma unroll
  for (int m = 1; m < 64; m <<= 1) {
    ssi += __shfl_xor(ssi, m);
    ssc += __shfl_xor(ssc, m);
  }
  float ri = 1.0f / fmaxf(sqrtf(ssi), 1e-12f);
  float rc = 1.0f / fmaxf(sqrtf(ssc), 1e-12f);
  float ax = vi.x*ri, ay = vi.y*ri, az = vi.z*ri, aw = vi.w*ri;
  float cx = vc.x*rc, cy = vc.y*rc, cz = vc.z*rc, cw = vc.w*rc;
  ushort4 ua, uc;
  ua.x = f2bf(ax); ua.y = f2bf(ay); ua.z = f2bf(az); ua.w = f2bf(aw);
  uc.x = f2bf(cx); uc.y = f2bf(cy); uc.z = f2bf(cz); uc.w = f2bf(cw);
  ((ushort4*)(imn + (size_t)w * D))[lane] = ua;
  ((ushort4*)(capn + (size_t)w * D))[lane] = uc;
  float d = ax*cx + ay*cy + az*cz + aw*cw;
  #pragma unroll
  for (int m = 1; m < 64; m <<= 1) d += __shfl_xor(d, m);
  if (lane == 0) diag[w] = d * INV_T;
}

// Kernel 2: BARRIER-FREE private-B GEMM.
// Block (512 thr, 8 waves) = 128 rows x 2048 cols; grid 256 = 64 bm x 4 cg.
// Each wave owns a PRIVATE 64-col strip per 512-col tile and stages its own
// B into its own 2x4KB LDS dbuf -> no cross-wave staging dependency -> ONE
// barrier total (post-A-prologue); waves free-run (m114 TLP inside 1 block).
// A: [128 rows][256 K] resident, 8x8KB slices, immutable after prologue.
// All waits are per-wave counted vmcnt on the wave's own loads.
// Swizzle (r6/r8/r13-verified, 0 conflicts): slot(row,u) holds global
// u^((row>>1)&3); pre-swizzled source; cc = kb ^ ((rb>>1)&3)*8 on reads.
__global__ __launch_bounds__(512) void gemm_exp_kernel(
    const ushort* __restrict__ A, const ushort* __restrict__ Bm,
    float* __restrict__ rowpart, float* __restrict__ colpart, int N) {
  __shared__ ushort As[8][128 * 32];      // 64 KB, immutable after prologue
  __shared__ ushort Bsh[8][2][64 * 32];   // 64 KB, per-wave private dbuf
  int bm = blockIdx.x >> 2;   // 0..63 : rows [bm*128, +128)
  int cg = blockIdx.x & 3;    // 0..3  : tiles T = cg*4+j, cols [T*512, +512)
  int tid = threadIdx.x;
  int lane = tid & 63;
  int wv = tid >> 6;
  int rb = lane & 15;
  int kb = (lane >> 4) * 8;
  int cc = kb ^ (((rb >> 1) & 3) * 8);

  // A staging: thread covers row tid>>2, unit tid&3 (linear dest tid*16B);
  // source unit pre-swizzled (tid&3)^((tid>>3)&3).
  int arow = tid >> 2;
  int ascol = 8 * ((tid & 3) ^ ((tid >> 3) & 3));
  const ushort* agS = A + ((size_t)bm * 128 + arow) * D + ascol;

  // B staging (per wave, load i covers its cols i*16+(lane>>2)):
  // dest linear i*512 + lane*8 elems; source unit (lane&3)^((lane>>3)&3).
  int su = 8 * ((lane & 3) ^ ((lane >> 3) & 3));
  const ushort* bgS = Bm + ((size_t)(wv * 64 + (lane >> 2))) * D + su;

  f32x4 acc[8][4];

#define VMWAIT(n) asm volatile("s_waitcnt vmcnt(" #n ")" ::: "memory")
#define LGKM0() asm volatile("s_waitcnt lgkmcnt(0)" ::: "memory")
#define BARRIER() asm volatile("s_barrier" ::: "memory")

#define STAGE_A(c)                                                           \
  __builtin_amdgcn_global_load_lds((as1_void*)(agS + (c) * 32),              \
      (as3_void*)(&As[c][tid * 8]), 16, 0, 0);

#define STAGE_B(P, T, KT) {                                                  \
    const ushort* bp = bgS + (size_t)(T) * 512 * D + (KT) * 32;              \
    _Pragma("unroll")                                                        \
    for (int i = 0; i < 4; ++i)                                              \
      __builtin_amdgcn_global_load_lds(                                      \
          (as1_void*)(bp + (size_t)i * 16 * D),                              \
          (as3_void*)(&Bsh[wv][P][i * 512 + lane * 8]), 16, 0, 0);           \
  }

#define READ_A(AF, KT)                                                      \
  { _Pragma("unroll") for (int mi = 0; mi < 8; ++mi)                        \
      AF[mi] = *(const bf16x8*)(&As[KT][(mi * 16 + rb) * 32 + cc]); }

#define READ_B(BF, P)                                                       \
  { _Pragma("unroll") for (int ni = 0; ni < 4; ++ni)                        \
      BF[ni] = *(const bf16x8*)(&Bsh[wv][P][(ni * 16 + rb) * 32 + cc]); }

#define MFMAS(AF, FB, CZ)                                                   \
  { __builtin_amdgcn_s_setprio(1);                                          \
    _Pragma("unroll") for (int mi = 0; mi < 8; ++mi)                        \
      _Pragma("unroll") for (int ni = 0; ni < 4; ++ni)                      \
        acc[mi][ni] = __builtin_amdgcn_mfma_f32_16x16x32_bf16(              \
            AF[mi], FB[ni],                                                 \
            (CZ) ? (f32x4){0.f, 0.f, 0.f, 0.f} : acc[mi][ni], 0, 0, 0);     \
    __builtin_amdgcn_s_setprio(0); }

#define EPILOGUE(T) {                                                         \
    _Pragma("unroll")                                                         \
    for (int mi = 0; mi < 8; ++mi)                                            \
      _Pragma("unroll")                                                       \
      for (int ni = 0; ni < 4; ++ni)                                          \
        _Pragma("unroll")                                                     \
        for (int r = 0; r < 4; ++r)                                           \
          acc[mi][ni][r] = __expf(acc[mi][ni][r] * INV_T);                    \
    bool sb0 = (lane & 1) != 0, sb1 = (lane & 2) != 0;                        \
    _Pragma("unroll")                                                         \
    for (int mi = 0; mi < 8; ++mi) {                                          \
      float v0 = acc[mi][0][0] + acc[mi][1][0] + acc[mi][2][0] + acc[mi][3][0]; \
      float v1 = acc[mi][0][1] + acc[mi][1][1] + acc[mi][2][1] + acc[mi][3][1]; \
      float v2 = acc[mi][0][2] + acc[mi][1][2] + acc[mi][2][2] + acc[mi][3][2]; \
      float v3 = acc[mi][0][3] + acc[mi][1][3] + acc[mi][2][3] + acc[mi][3][3]; \
      float h0 = (sb0 ? v1 : v0) + __shfl_xor(sb0 ? v0 : v1, 1);              \
      float h1 = (sb0 ? v3 : v2) + __shfl_xor(sb0 ? v2 : v3, 1);              \
      float g  = (sb1 ? h1 : h0) + __shfl_xor(sb1 ? h0 : h1, 2);              \
      g += __shfl_xor(g, 4);                                                  \
      g += __shfl_xor(g, 8);                                                  \
      if ((lane & 12) == 0)                                                   \
        rowpart[(size_t)((T) * 8 + wv) * N + bm * 128 + mi * 16 +             \
                (lane >> 4) * 4 + (lane & 3)] = g;                            \
    }                                                                         \
    _Pragma("unroll")                                                         \
    for (int ni = 0; ni < 4; ++ni) {                                          \
      float v = 0.f;                                                          \
      _Pragma("unroll")                                                       \
      for (int mi = 0; mi < 8; ++mi)                                          \
        _Pragma("unroll")                                                     \
        for (int r = 0; r < 4; ++r)                                           \
          v += acc[mi][ni][r];                                                \
      v += __shfl_xor(v, 16); v += __shfl_xor(v, 32);                         \
      if (lane < 16)                                                          \
        colpart[(size_t)bm * N + (T) * 512 + wv * 64 + ni * 16 + lane] = v;   \
    }                                                                         \
  }

  // ---- Prologue: A (8 loads) + own B(tile0, ch0, ch1). One barrier total.
  int T0 = cg * 4;
  STAGE_A(0) STAGE_A(1) STAGE_A(2) STAGE_A(3)
  STAGE_A(4) STAGE_A(5) STAGE_A(6) STAGE_A(7)
  STAGE_B(0, T0, 0)
  STAGE_B(1, T0, 1)
  VMWAIT(8);    // own A done (leaves ch0, ch1)
  BARRIER();    // all waves' A landed; As immutable hereafter
  VMWAIT(4);    // ch0 done (leaves ch1)
  bf16x8 fbA[4], fbB[4];
  READ_B(fbA, 0)

  for (int j = 0; j < 4; ++j) {
    int T = cg * 4 + j;
    bf16x8 af[8];
    // body 0: chunk 0 (fbA). Tile boundary drain for j>0.
    LGKM0();
    READ_A(af, 0)
    if (j > 0) { VMWAIT(0); }          // drains prior ch1' + epilogue stores
    STAGE_B(0, T, 2)
    if (j == 0) { VMWAIT(4); }         // ch1 done (leaves ch2)
    READ_B(fbB, 1)
    MFMAS(af, fbA, 1)
    // body 1: chunk 1 (fbB); stage ch3; wait ch2.
    LGKM0(); STAGE_B(1, T, 3) READ_A(af, 1) VMWAIT(4); READ_B(fbA, 0)
    MFMAS(af, fbB, 0)
    // body 2: chunk 2; stage ch4; wait ch3.
    LGKM0(); STAGE_B(0, T, 4) READ_A(af, 2) VMWAIT(4); READ_B(fbB, 1)
    MFMAS(af, fbA, 0)
    // body 3: chunk 3; stage ch5; wait ch4.
    LGKM0(); STAGE_B(1, T, 5) READ_A(af, 3) VMWAIT(4); READ_B(fbA, 0)
    MFMAS(af, fbB, 0)
    // body 4: chunk 4; stage ch6; wait ch5.
    LGKM0(); STAGE_B(0, T, 6) READ_A(af, 4) VMWAIT(4); READ_B(fbB, 1)
    MFMAS(af, fbA, 0)
    // body 5: chunk 5; stage ch7; wait ch6.
    LGKM0(); STAGE_B(1, T, 7) READ_A(af, 5) VMWAIT(4); READ_B(fbA, 0)
    MFMAS(af, fbB, 0)
    // body 6: chunk 6; stage next-tile ch0; wait ch7.
    LGKM0();
    if (j < 3) { STAGE_B(0, T + 1, 0) READ_A(af, 6) VMWAIT(4); }
    else       { READ_A(af, 6) VMWAIT(0); }
    READ_B(fbB, 1)
    MFMAS(af, fbA, 0)
    // body 7: chunk 7; stage next-tile ch1; wait+read next-tile ch0.
    LGKM0();
    if (j < 3) { STAGE_B(1, T + 1, 1) READ_A(af, 7) VMWAIT(4); READ_B(fbA, 0) }
    else       { READ_A(af, 7) }
    MFMAS(af, fbB, 0)
    EPILOGUE(T)
  }
  VMWAIT(0);  // retire final stores

#undef EPILOGUE
#undef MFMAS
#undef READ_B
#undef READ_A
#undef STAGE_B
#undef STAGE_A
#undef VMWAIT
#undef LGKM0
#undef BARRIER
}

// Kernel 3: partial reduction + per-sample loss + atomic accumulate into out.
__global__ __launch_bounds__(256) void reduce_kernel(
    const float* __restrict__ rowpart, const float* __restrict__ colpart,
    const float* __restrict__ diag, float* __restrict__ out,
    int N, int NPr, int NPc) {
  __shared__ float redr[4][64], redc[4][64];
  int w = threadIdx.x >> 6, s = threadIdx.x & 63;
  int i = blockIdx.x * 64 + s;
  float rs = 0.f, cs = 0.f;
  for (int k = w; k < NPr; k += 4) rs += rowpart[(size_t)k * N + i];
  for (int k = w; k < NPc; k += 4) cs += colpart[(size_t)k * N + i];
  redr[w][s] = rs; redc[w][s] = cs;
  __syncthreads();
  if (w == 0) {
    float R = redr[0][s] + redr[1][s] + redr[2][s] + redr[3][s];
    float C = redc[0][s] + redc[1][s] + redc[2][s] + redc[3][s];
    float l = logf(R) + logf(C) - 2.0f * diag[i];
    #pragma unroll
    for (int m = 1; m < 64; m <<= 1) l += __shfl_xor(l, m);
    if (s == 0) atomicAdd(out, l * (0.5f / (float)N));
  }
}

extern "C" void kernel_launch(void* const* d_in, const int* in_sizes, int n_in,
                              void* d_out, int out_size, void* d_ws, size_t ws_size,
                              hipStream_t stream) {
  const float* images = (const float*)d_in[0];
  const float* captions = (const float*)d_in[1];
  int N = in_sizes[0] / D;   // 8192
  int NPr = 128;             // 16 tiles x 8 waves
  int NPc = 64;              // 64 bm row-panels
  char* w = (char*)d_ws;
  size_t off = 0;
  ushort* imn  = (ushort*)(w + off); off += (size_t)N * D * 2;
  ushort* capn = (ushort*)(w + off); off += (size_t)N * D * 2;
  float* diag    = (float*)(w + off); off += (size_t)N * 4;
  float* rowpart = (float*)(w + off); off += (size_t)NPr * N * 4;
  float* colpart = (float*)(w + off); off += (size_t)NPc * N * 4;
  float* out = (float*)d_out;

  normalize_kernel<<<N / 4, 256, 0, stream>>>(images, captions, imn, capn, diag, N);
  gemm_exp_kernel<<<256, 512, 0, stream>>>(imn, capn, rowpart, colpart, N);
  hipMemsetAsync(out, 0, sizeof(float), stream);
  reduce_kernel<<<N / 64, 256, 0, stream>>>(rowpart, colpart, diag, out, N, NPr, NPc);
}